// Round 11
// baseline (312.462 us; speedup 1.0000x reference)
//
#include <hip/hip_runtime.h>
#include <stdint.h>

#define N_BATCH 32
#define CHN     256
#define HW      56
#define HP      58

// xpad layout (uint4 "cells" of 4 u32 = 128 channel-bits):
//   cell(n, hp, h, wp) = ((n*58 + hp)*2 + h)*58 + wp,  h = channel-half
#define XPAD_CELLS (N_BATCH * HP * 2 * HP)   // 215,296 cells
#define XPAD_U32   (XPAD_CELLS * 4)

// ---------------- fused prep (UNCHANGED from verified baseline) -------------
__global__ __launch_bounds__(256) void prep_kernel(const float* __restrict__ x,
                                                   const float* __restrict__ wsrc,
                                                   uint32_t* __restrict__ xpad,
                                                   uint32_t* __restrict__ wbits,
                                                   int* __restrict__ wpop) {
    __shared__ int part[9][4];
    int bid  = blockIdx.x;
    int t    = threadIdx.x;
    int lane = t & 63;

    if (bid < 784) {
        int tid = bid * 256 + t;          // 0..200703
        int n   = tid / 6272;             // 6272 = 3136 px * 2 halves
        int rem = tid - n * 6272;
        int hf  = rem / 3136;             // channel half
        int pq  = rem - hf * 3136;        // pixel in plane; lane-consecutive

        const float* src = x + ((size_t)(n * 256 + hf * 128)) * 3136 + pq;
        uint32_t b0 = 0, b1 = 0, b2 = 0, b3 = 0;
#pragma unroll
        for (int g = 0; g < 8; g++) {
            float v[16];
#pragma unroll
            for (int i = 0; i < 16; i++) v[i] = src[(size_t)(g * 16 + i) * 3136];
#pragma unroll
            for (int i = 0; i < 16; i++) {
                int c = g * 16 + i;       // 0..127 within half
                uint32_t b = v[i] > 0.0f ? 1u : 0u;
                if ((c >> 5) == 0) b0 |= b << (c & 31);
                else if ((c >> 5) == 1) b1 |= b << (c & 31);
                else if ((c >> 5) == 2) b2 |= b << (c & 31);
                else b3 |= b << (c & 31);
            }
        }
        int h = pq / 56;
        int w = pq - h * 56;
        uint32_t cell = ((uint32_t)(n * HP + h + 1) * 2 + hf) * HP + (w + 1);
        ((uint4*)xpad)[cell] = make_uint4(b0, b1, b2, b3);
    } else if (bid < 841) {
        int u = (bid - 784) * 256 + t;
        if (u < 14592) {
            int p = u / 228;
            int e = u - p * 228;
            int n = p >> 1, h = p & 1;
            int hp, wp;
            if (e < 58)       { hp = 0;       wp = e;       }
            else if (e < 116) { hp = 57;      wp = e - 58;  }
            else if (e < 172) { hp = e - 115; wp = 0;       }
            else              { hp = e - 171; wp = 57;      }
            uint32_t cell = ((uint32_t)(n * HP + hp) * 2 + h) * HP + wp;
            ((uint4*)xpad)[cell] = make_uint4(0u, 0u, 0u, 0u);
        }
    } else {
        int o  = bid - 841;
        int wv = t >> 6;
        const float* p = wsrc + ((size_t)o * 256 + t) * 9;
        float v[9];
#pragma unroll
        for (int tap = 0; tap < 9; tap++) v[tap] = p[tap];
#pragma unroll
        for (int tap = 0; tap < 9; tap++) {
            unsigned long long m = __ballot(v[tap] > 0.0f);
            if (lane == 0) {
                wbits[(size_t)(o * 9 + tap) * 8 + 2 * wv]     = (uint32_t)m;
                wbits[(size_t)(o * 9 + tap) * 8 + 2 * wv + 1] = (uint32_t)(m >> 32);
                part[tap][wv] = __builtin_popcountll(m);
            }
        }
        __syncthreads();
        if (t < 9) wpop[o * 9 + t] = part[t][0] + part[t][1] + part[t][2] + part[t][3];
    }
}

// ---------------- binary conv: X via scalar loads, W in ~60 VGPRs -----------
// Allocator law from R5/R7/R8/R9: it will not carry >~64 VGPRs of long-lived
// values here (pins included) -- it demotes to LDS re-reads / AGPR shuffles.
// So the design needs <=~60 VGPRs: X is WAVE-UNIFORM -> move it to the SGPR
// file via scalar loads (readfirstlane-forced uniform address on a const
// __restrict__ pointer promotes to s_load_dwordx4; SMEM pipe was idle).
// No sx staging, no staging barrier. Per px: 36 v_xor(s,v) + 36 v_bcnt.
// Block = (h, n, o-half); wave wv: hf = wv>>1, og = wv&1; lane owns one
// o = oh*128 + og*64 + lane. hf0/hf1 write int16 partials (1152-2*acc; hf0
// carries the edge correction) to obuf halves; drain sums. LDS 29.2 KB.
__global__ __launch_bounds__(256, 2)
void conv_kernel(const uint32_t* __restrict__ xpad,
                 const uint32_t* __restrict__ wbits,
                 const int* __restrict__ wpop,
                 float* __restrict__ out) {
    __shared__ short obuf[2][128][57];        // 29,184 B (57 coprime w/ 32 banks)

    int t    = threadIdx.x;
    int lane = t & 63;
    int wv   = t >> 6;
    int hf   = wv >> 1;                       // channel half (wave-uniform)
    int og   = wv & 1;                        // o-group within the half
    int h    = blockIdx.x;                    // output row 0..55
    int n    = blockIdx.y;
    int oh   = blockIdx.z;                    // o-half: o in [oh*128, oh*128+128)

    // per-lane: one o, one channel half -> 9 uint4 of W (36 VGPR)
    int ol = og * 64 + lane;                  // 0..127 within the o-half
    int o  = oh * 128 + ol;
    uint4 W[9];
#pragma unroll
    for (int tap = 0; tap < 9; tap++)
        W[tap] = *(const uint4*)(wbits + ((size_t)o * 9 + tap) * 8 + hf * 4);

    int pa[9];                                // full-256 popcounts; hf0 only
    if (hf == 0) {
        const int* wpa = wpop + (size_t)o * 9;
#pragma unroll
        for (int i = 0; i < 9; i++) pa[i] = wpa[i];
    }

    // wave-uniform X base: row h+r of my hf starts at cell
    //   ((n*HP + h + r)*2 + hf)*HP ; row stride = 2*HP cells
    int rowbase = __builtin_amdgcn_readfirstlane(((n * HP + h) * 2 + hf) * HP);
    const uint4* xr = (const uint4*)xpad + rowbase;

    short* ob  = &obuf[hf][ol][0];
    bool hedge = (h == 0) | (h == 55);

#pragma unroll 1
    for (int w = 0; w < 56; w++) {
        int a0 = 0, a1 = 0, a2 = 0, a3 = 0;   // 4 independent bcnt chains
#pragma unroll
        for (int r = 0; r < 3; r++)
#pragma unroll
            for (int dw = 0; dw < 3; dw++) {
                uint4 xc = xr[r * (2 * HP) + w + dw];   // uniform -> s_load_dwordx4
                uint4 wc = W[r * 3 + dw];
                a0 += __builtin_popcount(xc.x ^ wc.x);
                a1 += __builtin_popcount(xc.y ^ wc.y);
                a2 += __builtin_popcount(xc.z ^ wc.z);
                a3 += __builtin_popcount(xc.w ^ wc.w);
            }
        int vp = 1152 - 2 * ((a0 + a1) + (a2 + a3));
        if (hf == 0) {                        // full edge correction on hf0
            if (hedge | (w == 0) | (w == 55)) {
                int ca = 0;
#pragma unroll
                for (int dh = 0; dh < 3; dh++)
#pragma unroll
                    for (int dw = 0; dw < 3; dw++)
                        if ((unsigned)(h + dh - 1) >= 56u || (unsigned)(w + dw - 1) >= 56u)
                            ca += 256 - 2 * pa[dh * 3 + dw];
                vp -= ca;
            }
        }
        ob[w] = (short)vp;
    }

    __syncthreads();                          // partials cross hf waves

    // drain: wave wv sums the two hf partials for o_local in [wv*32, wv*32+32)
    if (lane < 56) {
        int base = wv * 32;
        float* orow = out + (((size_t)n * 256 + oh * 128 + base) * 56 + h) * 56 + lane;
#pragma unroll 8
        for (int i = 0; i < 32; i++) {
            int v = (int)obuf[0][base + i][lane] + (int)obuf[1][base + i][lane];
            orow[(size_t)i * 3136] = (float)v;
        }
    }
}

extern "C" void kernel_launch(void* const* d_in, const int* in_sizes, int n_in,
                              void* d_out, int out_size, void* d_ws, size_t ws_size,
                              hipStream_t stream) {
    const float* x    = (const float*)d_in[0];
    const float* wsrc = (const float*)d_in[1];
    float* out = (float*)d_out;

    uint32_t* xpad  = (uint32_t*)d_ws;                    // 3.44 MB
    uint32_t* wbits = xpad + XPAD_U32;                    // 18432 u32
    int*      wpop  = (int*)(wbits + 256 * 9 * 8);        // 2304 int

    prep_kernel<<<1097, 256, 0, stream>>>(x, wsrc, xpad, wbits, wpop);
    conv_kernel<<<dim3(HW, N_BATCH, 2), 256, 0, stream>>>(xpad, wbits, wpop, out);
}